// Round 14
// baseline (232.511 us; speedup 1.0000x reference)
//
#include <hip/hip_runtime.h>
#include <hip/hip_bf16.h>
#include <stdint.h>

typedef __bf16 bf16x8 __attribute__((ext_vector_type(8)));
typedef float  f32x4  __attribute__((ext_vector_type(4)));
typedef unsigned uint4v __attribute__((ext_vector_type(4)));
using bf16 = __hip_bfloat16;

#define NNODES 8192
#define FIN    8256      // 8192 + 64
#define NCOL   192       // 128 (W1) + 64 (W2 top)
#define KT32   258       // 8256 / 32

// ---- workspace layout (bytes) ----
enum : size_t {
  WCT_OFF  = 0,            // bf16 wctf [258][12][64][8]  3,170,304
  CNT_OFF  = 3170304,      // int  [8192]
  OFF_OFF  = 3203072,      // int  [8193]
  CUR_OFF  = 3236096,      // int  [8192]
  DNV_OFF  = 3268864,      // f32  [8192]
  CSR_OFF  = 3301632,      // int  [262144]
  H1_OFF   = 4350208,      // bf16 [8192][128]
  HX2_OFF  = 8544512,      // f32  [8192][64]
  RU_OFF   = 10641664,     // f32  [8192][128]
  H2_OFF   = 14835968,     // bf16 [8192][64]
  YP_OFF   = 16933120,     // f32  [ksplit][8192][192]
  YP_SLICE = 6291456
};

__global__ void k_zero_i(int* p, int n) {
  int i = blockIdx.x * 256 + threadIdx.x;
  if (i < n) p[i] = 0;
}

__global__ void k_out_zero(float* out) {
  int i = blockIdx.x * 256 + threadIdx.x;
  if (i < NNODES * 64) out[i] = 0.f;   // diagnostic signature if ws too small
}

// Build B in MFMA-fragment order: wctf[((t*12+nf)*64+lane)*8+j] =
//   Wc[k = t*32 + (lane>>4)*8 + j][col = nf*16 + (lane&15)]
__global__ void k_prep_wctf(const float* __restrict__ W1, const float* __restrict__ W2,
                            bf16* __restrict__ wctf) {
  int gid = blockIdx.x * 256 + threadIdx.x;
  if (gid >= KT32 * 12 * 64) return;
  int t = gid / 768;
  int rem = gid - t * 768;
  int nf = rem >> 6, lane = rem & 63;
  int col = nf * 16 + (lane & 15);
  int k0 = t * 32 + (lane >> 4) * 8;
  union { bf16 h[8]; uint4 v; } u;
#pragma unroll
  for (int j = 0; j < 8; ++j) {
    int k = k0 + j;
    float v;
    if (col < 128)      v = W1[(size_t)k * 128 + col];
    else if (k < 8192)  v = W2[(size_t)k * 64 + (col - 128)];
    else                v = 0.f;
    u.h[j] = __float2bfloat16(v);
  }
  *(uint4*)(wctf + (size_t)gid * 8) = u.v;
}

__global__ void k_hist(const int* __restrict__ ei, int E, int* cnt) {
  int e = blockIdx.x * 256 + threadIdx.x;
  if (e < E) atomicAdd(&cnt[ei[E + e]], 1);
}

__global__ void k_scan(const int* __restrict__ cnt, int* __restrict__ offs,
                       int* __restrict__ cur, float* __restrict__ dinv) {
  __shared__ int part[256];
  int tid = threadIdx.x;
  int base = tid * 32;
  int s = 0;
#pragma unroll
  for (int j = 0; j < 32; j++) s += cnt[base + j];
  part[tid] = s;
  __syncthreads();
  for (int off = 1; off < 256; off <<= 1) {
    int a = (tid >= off) ? part[tid - off] : 0;
    __syncthreads();
    part[tid] += a;
    __syncthreads();
  }
  int run = (tid == 0) ? 0 : part[tid - 1];
  for (int j = 0; j < 32; j++) {
    int c = cnt[base + j];
    offs[base + j] = run;
    cur[base + j]  = run;
    dinv[base + j] = rsqrtf((float)(c + 1));
    run += c;
  }
  if (tid == 255) offs[NNODES] = run;
}

__global__ void k_fill(const int* __restrict__ ei, int E, int* cur, int* __restrict__ csr) {
  int e = blockIdx.x * 256 + threadIdx.x;
  if (e < E) {
    int d = ei[E + e];
    int p = atomicAdd(&cur[d], 1);
    csr[p] = ei[e];
  }
}

__device__ __forceinline__ bf16x8 pack8(float4 a, float4 b) {
  union { bf16 h[8]; bf16x8 v; } u;
  u.h[0] = __float2bfloat16(a.x); u.h[1] = __float2bfloat16(a.y);
  u.h[2] = __float2bfloat16(a.z); u.h[3] = __float2bfloat16(a.w);
  u.h[4] = __float2bfloat16(b.x); u.h[5] = __float2bfloat16(b.y);
  u.h[6] = __float2bfloat16(b.z); u.h[7] = __float2bfloat16(b.w);
  return u.v;
}

union F4 { uint4v u; float4 f; bf16x8 h; };

__device__ __forceinline__ void gld16(void* ldsdst, const void* gsrc) {
  __builtin_amdgcn_global_load_lds(
      (__attribute__((address_space(1))) void*)gsrc,
      (__attribute__((address_space(3))) void*)ldsdst, 16, 0, 0);
}

// C = [x | hidden] @ Wc : M=8192, N=192, K=8256
// WAVE-AUTONOMOUS pipeline: 1 wave/block (64 thr), 32-row tile, NO barriers.
// A (HBM): triple-buffered LDS, 2 iterations in flight; B (L2): double-buffered,
// 1 iteration. Issue order B-then-A => steady-state s_waitcnt vmcnt(20) waits
// only for stage(t). Reads via asm ds_read + lgkmcnt(0) + sched_barrier(0)
// (R10 mechanism) so no compiler-inserted drain. LDS 36KB -> 4 blocks/CU.
__global__ __launch_bounds__(64, 1) void k_gemm(const float* __restrict__ x,
                                                const float* __restrict__ hid,
                                                const bf16* __restrict__ wctf,
                                                float* __restrict__ yp,
                                                bf16* __restrict__ h1d,
                                                float* __restrict__ hx2d,
                                                int tpc) {
  __shared__ __align__(1024) unsigned char smem[36864];  // A: 3 x 4KB @0, B: 2 x 12KB @12288
  const int lane = threadIdx.x & 63;
  const int rl = lane & 15, g = lane >> 4;
  const int m0 = blockIdx.x * 32;
  const int chunk = blockIdx.y;
  const int t_lo = chunk * tpc;
  const int t_hi = (t_lo + tpc > KT32) ? KT32 : (t_lo + tpc);
  const int nt = t_hi - t_lo;
  if (nt <= 0) return;

  // A staging: 256 units of 16B (32 rows x 8 slots), pre-swizzled source
  const float* asx[4]; const float* ash[4];
#pragma unroll
  for (int q = 0; q < 4; ++q) {
    int i = q * 64 + lane, row = i >> 3, s = i & 7;
    int sel = (s ^ (row & 7)) << 2;
    asx[q] = x + (size_t)(m0 + row) * 8192 + sel;
    ash[q] = hid + (size_t)(m0 + row) * 64 + sel;
  }
  const bf16* bsrc = wctf + (size_t)lane * 8;   // + t*6144 + q*512 (elems)

#define STAGE_A(buf, t) do {                                                   \
    const int _t = (t);                                                        \
    unsigned _d = (unsigned)(buf) * 4096u;                                     \
    if (_t < 256) {                                                            \
      const int _k = _t * 32;                                                  \
      _Pragma("unroll")                                                        \
      for (int q = 0; q < 4; ++q)                                              \
        gld16(smem + _d + (unsigned)(q * 64 + lane) * 16u, asx[q] + _k);       \
    } else {                                                                   \
      const int _k = (_t - 256) * 32;                                          \
      _Pragma("unroll")                                                        \
      for (int q = 0; q < 4; ++q)                                              \
        gld16(smem + _d + (unsigned)(q * 64 + lane) * 16u, ash[q] + _k);       \
    }                                                                          \
  } while (0)

#define STAGE_B(buf, t) do {                                                   \
    const bf16* _bt = bsrc + (size_t)(t) * 6144;                               \
    unsigned _d = 12288u + (unsigned)(buf) * 12288u + (unsigned)lane * 16u;    \
    _Pragma("unroll")                                                          \
    for (int q = 0; q < 12; ++q)                                               \
      gld16(smem + _d + (unsigned)q * 1024u, _bt + (size_t)q * 512);           \
  } while (0)

  f32x4 acc0[12] = {};
  f32x4 acc1[12] = {};

  // fragment read lane offsets (match verified R8 mapping)
  const unsigned sl0 = (unsigned)((g * 2) ^ (rl & 7));
  const unsigned sl1 = (unsigned)((g * 2 + 1) ^ (rl & 7));
  const unsigned aA0 = (unsigned)rl * 128u + sl0 * 16u;          // row rl, lo
  const unsigned aA1 = (unsigned)rl * 128u + sl1 * 16u;          // row rl, hi
  const unsigned baseB = 12288u + (unsigned)lane * 16u;
  const unsigned ldsbase = (unsigned)(uintptr_t)&smem[0];

  // prologue: A(0), B(0), A(1)  (order matters for vmcnt math)
  STAGE_A(0, t_lo);
  STAGE_B(0, t_lo);
  if (nt > 1) STAGE_A(1, t_lo + 1);

  int r3 = 0;                       // li % 3
  int w3 = 2;                       // (li+2) % 3
  for (int li = 0; li < nt; ++li) {
    if (li + 1 < nt) STAGE_B((li + 1) & 1, t_lo + li + 1);
    if (li + 2 < nt) STAGE_A(w3, t_lo + li + 2);

    if (li + 2 < nt)      asm volatile("s_waitcnt vmcnt(20)" ::: "memory");
    else if (li + 1 < nt) asm volatile("s_waitcnt vmcnt(16)" ::: "memory");
    else                  asm volatile("s_waitcnt vmcnt(0)"  ::: "memory");
    __builtin_amdgcn_sched_barrier(0);

    const unsigned ar = ldsbase + (unsigned)r3 * 4096u;
    const unsigned br = ldsbase + baseB + (unsigned)(li & 1) * 12288u;
    F4 a00, a01, a10, a11, bv[12];
    asm volatile("ds_read_b128 %0, %1" : "=v"(a00.u) : "v"(ar + aA0));
    asm volatile("ds_read_b128 %0, %1" : "=v"(a01.u) : "v"(ar + aA1));
    asm volatile("ds_read_b128 %0, %1 offset:2048" : "=v"(a10.u) : "v"(ar + aA0));
    asm volatile("ds_read_b128 %0, %1 offset:2048" : "=v"(a11.u) : "v"(ar + aA1));
#pragma unroll
    for (int nf = 0; nf < 12; ++nf)
      asm volatile("ds_read_b128 %0, %1 offset:%c2"
                   : "=v"(bv[nf].u) : "v"(br), "i"(nf * 1024));
    asm volatile("s_waitcnt lgkmcnt(0)" ::: "memory");
    __builtin_amdgcn_sched_barrier(0);

    bf16x8 af0 = pack8(a00.f, a01.f);
    bf16x8 af1 = pack8(a10.f, a11.f);
#pragma unroll
    for (int nf = 0; nf < 12; ++nf) {
      acc0[nf] = __builtin_amdgcn_mfma_f32_16x16x32_bf16(af0, bv[nf].h, acc0[nf], 0, 0, 0);
      acc1[nf] = __builtin_amdgcn_mfma_f32_16x16x32_bf16(af1, bv[nf].h, acc1[nf], 0, 0, 0);
    }
    r3 = (r3 == 2) ? 0 : r3 + 1;
    w3 = (w3 == 2) ? 0 : w3 + 1;
  }
#undef STAGE_A
#undef STAGE_B

  // C/D layout (HW-verified): col = lane&15, row = (lane>>4)*4 + reg
  if (h1d) {  // direct mode (ksplit==1)
#pragma unroll
    for (int nf = 0; nf < 12; ++nf) {
      int col = nf * 16 + rl;
#pragma unroll
      for (int tt = 0; tt < 4; ++tt) {
        int ra = m0 + g * 4 + tt;
        int rb = ra + 16;
        if (col < 128) {
          h1d[(size_t)ra * 128 + col] = __float2bfloat16(acc0[nf][tt]);
          h1d[(size_t)rb * 128 + col] = __float2bfloat16(acc1[nf][tt]);
        } else {
          hx2d[(size_t)ra * 64 + (col - 128)] = acc0[nf][tt];
          hx2d[(size_t)rb * 64 + (col - 128)] = acc1[nf][tt];
        }
      }
    }
  } else {
    float* ypc = yp + (size_t)chunk * ((size_t)NNODES * NCOL);
#pragma unroll
    for (int nf = 0; nf < 12; ++nf) {
      int col = nf * 16 + rl;
#pragma unroll
      for (int tt = 0; tt < 4; ++tt) {
        int ra = m0 + g * 4 + tt;
        ypc[(size_t)ra * NCOL + col] = acc0[nf][tt];
        ypc[(size_t)(ra + 16) * NCOL + col] = acc1[nf][tt];
      }
    }
  }
}

// sum K-split partials (float4-vectorized); h1 -> bf16, hx2 -> fp32
__global__ void k_reduce4(const float* __restrict__ yp, bf16* __restrict__ h1,
                          float* __restrict__ hx2, int nch) {
  int u = blockIdx.x * 256 + threadIdx.x;      // < 8192*192/4
  float4 s = {0.f, 0.f, 0.f, 0.f};
  for (int c = 0; c < nch; c++) {
    float4 v = *(const float4*)(yp + (size_t)c * ((size_t)NNODES * NCOL) + (size_t)u * 4);
    s.x += v.x; s.y += v.y; s.z += v.z; s.w += v.w;
  }
  int e = u * 4;
  int i = e / NCOL, c = e - i * NCOL;          // float4 never straddles boundaries
  if (c < 128) {
    bf16* dst = h1 + (size_t)i * 128 + c;
    dst[0] = __float2bfloat16(s.x); dst[1] = __float2bfloat16(s.y);
    dst[2] = __float2bfloat16(s.z); dst[3] = __float2bfloat16(s.w);
  } else {
    *(float4*)(hx2 + (size_t)i * 64 + (c - 128)) = s;
  }
}

__device__ __forceinline__ float bflo(unsigned v) { return __uint_as_float(v << 16); }
__device__ __forceinline__ float bfhi(unsigned v) { return __uint_as_float(v & 0xffff0000u); }

__global__ void k_scat1(const bf16* __restrict__ h1b, const int* __restrict__ offs,
                        const int* __restrict__ csr, const float* __restrict__ dinv,
                        const float* __restrict__ b1, float* __restrict__ ru) {
  int node = blockIdx.x * 4 + (threadIdx.x >> 6);
  int lane = threadIdx.x & 63;
  const unsigned* h1u = (const unsigned*)h1b;
  float dd = dinv[node];
  unsigned vv = h1u[(size_t)node * 64 + lane];
  float ax = bflo(vv) * dd * dd, ay = bfhi(vv) * dd * dd;
  int e0 = offs[node], e1 = offs[node + 1];
  for (int e = e0; e < e1; ++e) {
    int s = csr[e];
    float nrm = dinv[s] * dd;
    unsigned wv = h1u[(size_t)s * 64 + lane];
    ax += bflo(wv) * nrm;
    ay += bfhi(wv) * nrm;
  }
  ax += b1[lane * 2];
  ay += b1[lane * 2 + 1];
  ax = 1.f / (1.f + expf(-ax));
  ay = 1.f / (1.f + expf(-ay));
  ru[(size_t)node * 128 + lane * 2]     = ax;
  ru[(size_t)node * 128 + lane * 2 + 1] = ay;
}

__global__ void k_rh(const float* __restrict__ ru, const float* __restrict__ hidden,
                     const float* __restrict__ hx2, const float* __restrict__ W2,
                     bf16* __restrict__ h2) {
  __shared__ float W2s[64][64];
  __shared__ float rhs[4][64];
  int tid = threadIdx.x;
#pragma unroll
  for (int t = 0; t < 16; ++t) {
    int idx = tid + 256 * t;
    int j = idx >> 6, c = idx & 63;
    W2s[j][c] = W2[(size_t)(8192 + j) * 64 + c];
  }
  int w = tid >> 6, lane = tid & 63;
  int i = blockIdx.x * 4 + w;
  float rv = ru[(size_t)(i >> 1) * 128 + ((i & 1) << 6) + lane];
  float hv = hidden[(size_t)i * 64 + lane];
  rhs[w][lane] = rv * hv;
  __syncthreads();
  float acc = hx2[(size_t)i * 64 + lane];
#pragma unroll 8
  for (int j = 0; j < 64; ++j) acc += rhs[w][j] * W2s[j][lane];
  h2[(size_t)i * 64 + lane] = __float2bfloat16(acc);
}

__global__ void k_scat2(const bf16* __restrict__ h2b, const int* __restrict__ offs,
                        const int* __restrict__ csr, const float* __restrict__ dinv,
                        const float* __restrict__ b2, const float* __restrict__ ru,
                        const float* __restrict__ hidden, float* __restrict__ out) {
  int node = blockIdx.x * 4 + (threadIdx.x >> 6);
  int lane = threadIdx.x & 63;
  const unsigned short* h2u = (const unsigned short*)h2b;
  float dd = dinv[node];
  float acc = bflo((unsigned)h2u[(size_t)node * 64 + lane]) * dd * dd;
  int e0 = offs[node], e1 = offs[node + 1];
  for (int e = e0; e < e1; ++e) {
    int s = csr[e];
    acc += bflo((unsigned)h2u[(size_t)s * 64 + lane]) * dinv[s] * dd;
  }
  acc += b2[lane];
  float cv = tanhf(acc);
  float u = ru[(size_t)(4096 + (node >> 1)) * 128 + ((node & 1) << 6) + lane];
  float hv = hidden[(size_t)node * 64 + lane];
  out[(size_t)node * 64 + lane] = u * hv + (1.f - u) * cv;
}

extern "C" void kernel_launch(void* const* d_in, const int* in_sizes, int n_in,
                              void* d_out, int out_size, void* d_ws, size_t ws_size,
                              hipStream_t stream) {
  (void)n_in; (void)out_size;
  const float* x   = (const float*)d_in[0];
  const float* hid = (const float*)d_in[1];
  const float* W1  = (const float*)d_in[2];
  const float* b1  = (const float*)d_in[3];
  const float* W2  = (const float*)d_in[4];
  const float* b2  = (const float*)d_in[5];
  const int*   ei  = (const int*)d_in[6];
  const int E = in_sizes[6] / 2;
  float* out = (float*)d_out;

  int ksplit;
  if      (ws_size >= YP_OFF + 8ull * YP_SLICE) ksplit = 8;
  else if (ws_size >= YP_OFF + 4ull * YP_SLICE) ksplit = 4;
  else if (ws_size >= YP_OFF + 2ull * YP_SLICE) ksplit = 2;
  else if (ws_size >= YP_OFF)                   ksplit = 1;
  else {
    k_out_zero<<<dim3(NNODES * 64 / 256), dim3(256), 0, stream>>>(out);
    return;
  }
  const int tpc = (KT32 + ksplit - 1) / ksplit;

  char* ws = (char*)d_ws;
  bf16*  wctf = (bf16*)(ws + WCT_OFF);
  int*   cnt  = (int*)(ws + CNT_OFF);
  int*   offs = (int*)(ws + OFF_OFF);
  int*   cur  = (int*)(ws + CUR_OFF);
  float* dinv = (float*)(ws + DNV_OFF);
  int*   csr  = (int*)(ws + CSR_OFF);
  bf16*  h1   = (bf16*)(ws + H1_OFF);
  float* hx2  = (float*)(ws + HX2_OFF);
  float* ru   = (float*)(ws + RU_OFF);
  bf16*  h2   = (bf16*)(ws + H2_OFF);
  float* yp   = (float*)(ws + YP_OFF);

  k_zero_i<<<dim3(32), dim3(256), 0, stream>>>(cnt, NNODES);
  k_prep_wctf<<<dim3((KT32 * 12 * 64 + 255) / 256), dim3(256), 0, stream>>>(W1, W2, wctf);
  k_hist<<<dim3((E + 255) / 256), dim3(256), 0, stream>>>(ei, E, cnt);
  k_scan<<<dim3(1), dim3(256), 0, stream>>>(cnt, offs, cur, dinv);
  k_fill<<<dim3((E + 255) / 256), dim3(256), 0, stream>>>(ei, E, cur, csr);
  if (ksplit == 1) {
    k_gemm<<<dim3(NNODES / 32, 1), dim3(64), 0, stream>>>(x, hid, wctf, nullptr, h1, hx2, tpc);
  } else {
    k_gemm<<<dim3(NNODES / 32, ksplit), dim3(64), 0, stream>>>(x, hid, wctf, yp, nullptr, nullptr, tpc);
    k_reduce4<<<dim3(NNODES * NCOL / 1024), dim3(256), 0, stream>>>(yp, h1, hx2, ksplit);
  }
  k_scat1<<<dim3(NNODES / 4), dim3(256), 0, stream>>>(h1, offs, csr, dinv, b1, ru);
  k_rh<<<dim3(NNODES / 4), dim3(256), 0, stream>>>(ru, hid, hx2, W2, h2);
  k_scat2<<<dim3(NNODES / 4), dim3(256), 0, stream>>>(h2, offs, csr, dinv, b2, ru, hid, out);
}

// Round 16
// 207.541 us; speedup vs baseline: 1.1203x; 1.1203x over previous
//
#include <hip/hip_runtime.h>
#include <hip/hip_bf16.h>
#include <stdint.h>

typedef __bf16 bf16x8 __attribute__((ext_vector_type(8)));
typedef float  f32x4  __attribute__((ext_vector_type(4)));
typedef unsigned uint4v __attribute__((ext_vector_type(4)));
using bf16 = __hip_bfloat16;

#define NNODES 8192
#define FIN    8256      // 8192 + 64
#define NCOL   192       // 128 (W1) + 64 (W2 top)
#define KT32   258       // 8256 / 32
#define BMB    128       // rows per block (4 waves x 32 rows each)

// ---- workspace layout (bytes) ----
enum : size_t {
  WCT_OFF  = 0,            // bf16 wctf [258][12][64][8]  3,170,304
  CNT_OFF  = 3170304,      // int  [8192]
  OFF_OFF  = 3203072,      // int  [8193]
  CUR_OFF  = 3236096,      // int  [8192]
  DNV_OFF  = 3268864,      // f32  [8192]
  CSR_OFF  = 3301632,      // int  [262144]
  H1_OFF   = 4350208,      // bf16 [8192][128]
  HX2_OFF  = 8544512,      // f32  [8192][64]
  RU_OFF   = 10641664,     // f32  [8192][128]
  H2_OFF   = 14835968,     // bf16 [8192][64]
  YP_OFF   = 16933120,     // f32  [ksplit][8192][192]
  YP_SLICE = 6291456
};

__global__ void k_zero_i(int* p, int n) {
  int i = blockIdx.x * 256 + threadIdx.x;
  if (i < n) p[i] = 0;
}

__global__ void k_out_zero(float* out) {
  int i = blockIdx.x * 256 + threadIdx.x;
  if (i < NNODES * 64) out[i] = 0.f;   // diagnostic signature if ws too small
}

// Build B in MFMA-fragment order: wctf[((t*12+nf)*64+lane)*8+j] =
//   Wc[k = t*32 + (lane>>4)*8 + j][col = nf*16 + (lane&15)]
__global__ void k_prep_wctf(const float* __restrict__ W1, const float* __restrict__ W2,
                            bf16* __restrict__ wctf) {
  int gid = blockIdx.x * 256 + threadIdx.x;
  if (gid >= KT32 * 12 * 64) return;
  int t = gid / 768;
  int rem = gid - t * 768;
  int nf = rem >> 6, lane = rem & 63;
  int col = nf * 16 + (lane & 15);
  int k0 = t * 32 + (lane >> 4) * 8;
  union { bf16 h[8]; uint4 v; } u;
#pragma unroll
  for (int j = 0; j < 8; ++j) {
    int k = k0 + j;
    float v;
    if (col < 128)      v = W1[(size_t)k * 128 + col];
    else if (k < 8192)  v = W2[(size_t)k * 64 + (col - 128)];
    else                v = 0.f;
    u.h[j] = __float2bfloat16(v);
  }
  *(uint4*)(wctf + (size_t)gid * 8) = u.v;
}

__global__ void k_hist(const int* __restrict__ ei, int E, int* cnt) {
  int e = blockIdx.x * 256 + threadIdx.x;
  if (e < E) atomicAdd(&cnt[ei[E + e]], 1);
}

__global__ void k_scan(const int* __restrict__ cnt, int* __restrict__ offs,
                       int* __restrict__ cur, float* __restrict__ dinv) {
  __shared__ int part[256];
  int tid = threadIdx.x;
  int base = tid * 32;
  int s = 0;
#pragma unroll
  for (int j = 0; j < 32; j++) s += cnt[base + j];
  part[tid] = s;
  __syncthreads();
  for (int off = 1; off < 256; off <<= 1) {
    int a = (tid >= off) ? part[tid - off] : 0;
    __syncthreads();
    part[tid] += a;
    __syncthreads();
  }
  int run = (tid == 0) ? 0 : part[tid - 1];
  for (int j = 0; j < 32; j++) {
    int c = cnt[base + j];
    offs[base + j] = run;
    cur[base + j]  = run;
    dinv[base + j] = rsqrtf((float)(c + 1));
    run += c;
  }
  if (tid == 255) offs[NNODES] = run;
}

__global__ void k_fill(const int* __restrict__ ei, int E, int* cur, int* __restrict__ csr) {
  int e = blockIdx.x * 256 + threadIdx.x;
  if (e < E) {
    int d = ei[E + e];
    int p = atomicAdd(&cur[d], 1);
    csr[p] = ei[e];
  }
}

__device__ __forceinline__ bf16x8 pack8(float4 a, float4 b) {
  union { bf16 h[8]; bf16x8 v; } u;
  u.h[0] = __float2bfloat16(a.x); u.h[1] = __float2bfloat16(a.y);
  u.h[2] = __float2bfloat16(a.z); u.h[3] = __float2bfloat16(a.w);
  u.h[4] = __float2bfloat16(b.x); u.h[5] = __float2bfloat16(b.y);
  u.h[6] = __float2bfloat16(b.z); u.h[7] = __float2bfloat16(b.w);
  return u.v;
}

union F4 { uint4v u; float4 f; bf16x8 h; };

__device__ __forceinline__ void gld16(void* ldsdst, const void* gsrc) {
  __builtin_amdgcn_global_load_lds(
      (__attribute__((address_space(1))) void*)gsrc,
      (__attribute__((address_space(3))) void*)ldsdst, 16, 0, 0);
}

// C = [x | hidden] @ Wc : M=8192, N=192, K=8256
// R8 geometry (4 waves share 128-row A tile + one B tile: 7 VMEM instr/thread/iter)
// + counted per-THREAD vmcnt (R15 bug: used tile-level counts; correct steady wait
// is vmcnt(7) = B(i+2)[3] + A(i+1)[4] newer than A(i)) + asm s_barrier so the
// memory legalizer cannot insert a vmcnt(0) drain.
__global__ __launch_bounds__(256, 2) void k_gemm(const float* __restrict__ x,
                                                 const float* __restrict__ hid,
                                                 const bf16* __restrict__ wctf,
                                                 float* __restrict__ yp,
                                                 bf16* __restrict__ h1d,
                                                 float* __restrict__ hx2d,
                                                 int tpc) {
  __shared__ __align__(1024) unsigned char smem[69632];  // A: 2x16KB @0, B: 3x12KB @32768
  const int tid = threadIdx.x;
  const int lane = tid & 63, w = tid >> 6;
  const int rl = lane & 15, g = lane >> 4;
  const int m0 = blockIdx.x * BMB;
  const int chunk = blockIdx.y;
  const int t_lo = chunk * tpc;
  const int t_hi = (t_lo + tpc > KT32) ? KT32 : (t_lo + tpc);
  const int nt = t_hi - t_lo;
  if (nt <= 0) return;

  // A staging sources (pre-swizzled): unit u = q*256+tid -> row=u>>3, slot s=u&7
  const float* asx[4]; const float* ash[4];
#pragma unroll
  for (int q = 0; q < 4; ++q) {
    int u = q * 256 + tid, row = u >> 3, s = u & 7;
    int sel = (s ^ (row & 7)) << 2;
    asx[q] = x + (size_t)(m0 + row) * 8192 + sel;
    ash[q] = hid + (size_t)(m0 + row) * 64 + sel;
  }

#define STAGE_A(buf, t) do {                                                    \
    const int _t = (t);                                                         \
    unsigned _d = (unsigned)(buf) * 16384u;                                     \
    if (_t < 256) {                                                             \
      const int _k = _t * 32;                                                   \
      _Pragma("unroll")                                                         \
      for (int q = 0; q < 4; ++q)                                               \
        gld16(smem + _d + (unsigned)(q * 256 + tid) * 16u, asx[q] + _k);        \
    } else {                                                                    \
      const int _k = (_t - 256) * 32;                                           \
      _Pragma("unroll")                                                         \
      for (int q = 0; q < 4; ++q)                                               \
        gld16(smem + _d + (unsigned)(q * 256 + tid) * 16u, ash[q] + _k);        \
    }                                                                           \
  } while (0)

#define STAGE_B(buf, t) do {                                                    \
    const bf16* _bt = wctf + (size_t)(t) * 6144;                                \
    unsigned _d = 32768u + (unsigned)(buf) * 12288u;                            \
    _Pragma("unroll")                                                           \
    for (int q = 0; q < 3; ++q)                                                 \
      gld16(smem + _d + (unsigned)(q * 256 + tid) * 16u,                        \
            _bt + (size_t)(q * 256 + tid) * 8);                                 \
  } while (0)

  f32x4 acc0[12] = {};
  f32x4 acc1[12] = {};

  // fragment read addresses (verified R8 mapping)
  const unsigned sl0 = (unsigned)((g * 2) ^ (rl & 7));
  const unsigned sl1 = (unsigned)((g * 2 + 1) ^ (rl & 7));
  const unsigned ldsbase = (unsigned)(uintptr_t)&smem[0];
  const unsigned aA0 = (unsigned)(w * 32 + rl) * 128u + sl0 * 16u;
  const unsigned aA1 = (unsigned)(w * 32 + rl) * 128u + sl1 * 16u;
  const unsigned bB  = 32768u + (unsigned)lane * 16u;

  // prologue (per-thread instr): A(0)=4, B(0)=3, B(1)=3
  STAGE_A(0, t_lo);
  STAGE_B(0, t_lo);
  if (nt > 1) STAGE_B(1, t_lo + 1);

  int b3r = 0, b3w = 2;   // i % 3, (i+2) % 3
  for (int i = 0; i < nt; ++i) {
    if (i + 2 < nt) STAGE_B(b3w, t_lo + i + 2);                 // 3 instr/thread
    if (i + 1 < nt) STAGE_A((i + 1) & 1, t_lo + i + 1);         // 4 instr/thread

    // per-thread queue (oldest->newest): B(i), [A(i-1) done], B(i+1), A(i), B(i+2), A(i+1)
    // need A(i),B(i) done -> wait = #newer-than-A(i)
    if (i + 2 < nt)      asm volatile("s_waitcnt vmcnt(7)" ::: "memory");  // B(i+2)+A(i+1)
    else if (i + 1 < nt) asm volatile("s_waitcnt vmcnt(4)" ::: "memory");  // A(i+1)
    else                 asm volatile("s_waitcnt vmcnt(0)" ::: "memory");
    asm volatile("s_barrier" ::: "memory");        // asm: legalizer can't add a drain

    const unsigned ar = ldsbase + (unsigned)(i & 1) * 16384u;
    const unsigned br = ldsbase + bB + (unsigned)b3r * 12288u;
    F4 a00, a01, a10, a11, bv[12];
    asm volatile("ds_read_b128 %0, %1" : "=v"(a00.u) : "v"(ar + aA0));
    asm volatile("ds_read_b128 %0, %1" : "=v"(a01.u) : "v"(ar + aA1));
    asm volatile("ds_read_b128 %0, %1 offset:2048" : "=v"(a10.u) : "v"(ar + aA0));
    asm volatile("ds_read_b128 %0, %1 offset:2048" : "=v"(a11.u) : "v"(ar + aA1));
#pragma unroll
    for (int nf = 0; nf < 12; ++nf)
      asm volatile("ds_read_b128 %0, %1 offset:%c2"
                   : "=v"(bv[nf].u) : "v"(br), "i"(nf * 1024));
    asm volatile("s_waitcnt lgkmcnt(0)" ::: "memory");
    __builtin_amdgcn_sched_barrier(0);

    bf16x8 af0 = pack8(a00.f, a01.f);
    bf16x8 af1 = pack8(a10.f, a11.f);
#pragma unroll
    for (int nf = 0; nf < 12; ++nf) {
      acc0[nf] = __builtin_amdgcn_mfma_f32_16x16x32_bf16(af0, bv[nf].h, acc0[nf], 0, 0, 0);
      acc1[nf] = __builtin_amdgcn_mfma_f32_16x16x32_bf16(af1, bv[nf].h, acc1[nf], 0, 0, 0);
    }
    asm volatile("s_barrier" ::: "memory");        // readers done before next overwrite
    b3r = (b3r == 2) ? 0 : b3r + 1;
    b3w = (b3w == 2) ? 0 : b3w + 1;
  }
#undef STAGE_A
#undef STAGE_B

  // C/D layout (HW-verified): col = lane&15, row = (lane>>4)*4 + reg
  if (h1d) {  // direct mode (ksplit==1)
#pragma unroll
    for (int nf = 0; nf < 12; ++nf) {
      int col = nf * 16 + rl;
#pragma unroll
      for (int tt = 0; tt < 4; ++tt) {
        int ra = m0 + w * 32 + g * 4 + tt;
        int rb = ra + 16;
        if (col < 128) {
          h1d[(size_t)ra * 128 + col] = __float2bfloat16(acc0[nf][tt]);
          h1d[(size_t)rb * 128 + col] = __float2bfloat16(acc1[nf][tt]);
        } else {
          hx2d[(size_t)ra * 64 + (col - 128)] = acc0[nf][tt];
          hx2d[(size_t)rb * 64 + (col - 128)] = acc1[nf][tt];
        }
      }
    }
  } else {
    float* ypc = yp + (size_t)chunk * ((size_t)NNODES * NCOL);
#pragma unroll
    for (int nf = 0; nf < 12; ++nf) {
      int col = nf * 16 + rl;
#pragma unroll
      for (int tt = 0; tt < 4; ++tt) {
        int ra = m0 + w * 32 + g * 4 + tt;
        ypc[(size_t)ra * NCOL + col] = acc0[nf][tt];
        ypc[(size_t)(ra + 16) * NCOL + col] = acc1[nf][tt];
      }
    }
  }
}

// sum K-split partials (float4-vectorized); h1 -> bf16, hx2 -> fp32
__global__ void k_reduce4(const float* __restrict__ yp, bf16* __restrict__ h1,
                          float* __restrict__ hx2, int nch) {
  int u = blockIdx.x * 256 + threadIdx.x;      // < 8192*192/4
  float4 s = {0.f, 0.f, 0.f, 0.f};
  for (int c = 0; c < nch; c++) {
    float4 v = *(const float4*)(yp + (size_t)c * ((size_t)NNODES * NCOL) + (size_t)u * 4);
    s.x += v.x; s.y += v.y; s.z += v.z; s.w += v.w;
  }
  int e = u * 4;
  int i = e / NCOL, c = e - i * NCOL;          // float4 never straddles boundaries
  if (c < 128) {
    bf16* dst = h1 + (size_t)i * 128 + c;
    dst[0] = __float2bfloat16(s.x); dst[1] = __float2bfloat16(s.y);
    dst[2] = __float2bfloat16(s.z); dst[3] = __float2bfloat16(s.w);
  } else {
    *(float4*)(hx2 + (size_t)i * 64 + (c - 128)) = s;
  }
}

__device__ __forceinline__ float bflo(unsigned v) { return __uint_as_float(v << 16); }
__device__ __forceinline__ float bfhi(unsigned v) { return __uint_as_float(v & 0xffff0000u); }

__global__ void k_scat1(const bf16* __restrict__ h1b, const int* __restrict__ offs,
                        const int* __restrict__ csr, const float* __restrict__ dinv,
                        const float* __restrict__ b1, float* __restrict__ ru) {
  int node = blockIdx.x * 4 + (threadIdx.x >> 6);
  int lane = threadIdx.x & 63;
  const unsigned* h1u = (const unsigned*)h1b;
  float dd = dinv[node];
  unsigned vv = h1u[(size_t)node * 64 + lane];
  float ax = bflo(vv) * dd * dd, ay = bfhi(vv) * dd * dd;
  int e0 = offs[node], e1 = offs[node + 1];
  for (int e = e0; e < e1; ++e) {
    int s = csr[e];
    float nrm = dinv[s] * dd;
    unsigned wv = h1u[(size_t)s * 64 + lane];
    ax += bflo(wv) * nrm;
    ay += bfhi(wv) * nrm;
  }
  ax += b1[lane * 2];
  ay += b1[lane * 2 + 1];
  ax = 1.f / (1.f + expf(-ax));
  ay = 1.f / (1.f + expf(-ay));
  ru[(size_t)node * 128 + lane * 2]     = ax;
  ru[(size_t)node * 128 + lane * 2 + 1] = ay;
}

__global__ void k_rh(const float* __restrict__ ru, const float* __restrict__ hidden,
                     const float* __restrict__ hx2, const float* __restrict__ W2,
                     bf16* __restrict__ h2) {
  __shared__ float W2s[64][64];
  __shared__ float rhs[4][64];
  int tid = threadIdx.x;
#pragma unroll
  for (int t = 0; t < 16; ++t) {
    int idx = tid + 256 * t;
    int j = idx >> 6, c = idx & 63;
    W2s[j][c] = W2[(size_t)(8192 + j) * 64 + c];
  }
  int w = tid >> 6, lane = tid & 63;
  int i = blockIdx.x * 4 + w;
  float rv = ru[(size_t)(i >> 1) * 128 + ((i & 1) << 6) + lane];
  float hv = hidden[(size_t)i * 64 + lane];
  rhs[w][lane] = rv * hv;
  __syncthreads();
  float acc = hx2[(size_t)i * 64 + lane];
#pragma unroll 8
  for (int j = 0; j < 64; ++j) acc += rhs[w][j] * W2s[j][lane];
  h2[(size_t)i * 64 + lane] = __float2bfloat16(acc);
}

__global__ void k_scat2(const bf16* __restrict__ h2b, const int* __restrict__ offs,
                        const int* __restrict__ csr, const float* __restrict__ dinv,
                        const float* __restrict__ b2, const float* __restrict__ ru,
                        const float* __restrict__ hidden, float* __restrict__ out) {
  int node = blockIdx.x * 4 + (threadIdx.x >> 6);
  int lane = threadIdx.x & 63;
  const unsigned short* h2u = (const unsigned short*)h2b;
  float dd = dinv[node];
  float acc = bflo((unsigned)h2u[(size_t)node * 64 + lane]) * dd * dd;
  int e0 = offs[node], e1 = offs[node + 1];
  for (int e = e0; e < e1; ++e) {
    int s = csr[e];
    acc += bflo((unsigned)h2u[(size_t)s * 64 + lane]) * dinv[s] * dd;
  }
  acc += b2[lane];
  float cv = tanhf(acc);
  float u = ru[(size_t)(4096 + (node >> 1)) * 128 + ((node & 1) << 6) + lane];
  float hv = hidden[(size_t)node * 64 + lane];
  out[(size_t)node * 64 + lane] = u * hv + (1.f - u) * cv;
}

extern "C" void kernel_launch(void* const* d_in, const int* in_sizes, int n_in,
                              void* d_out, int out_size, void* d_ws, size_t ws_size,
                              hipStream_t stream) {
  (void)n_in; (void)out_size;
  const float* x   = (const float*)d_in[0];
  const float* hid = (const float*)d_in[1];
  const float* W1  = (const float*)d_in[2];
  const float* b1  = (const float*)d_in[3];
  const float* W2  = (const float*)d_in[4];
  const float* b2  = (const float*)d_in[5];
  const int*   ei  = (const int*)d_in[6];
  const int E = in_sizes[6] / 2;
  float* out = (float*)d_out;

  int ksplit;
  if      (ws_size >= YP_OFF + 8ull * YP_SLICE) ksplit = 8;
  else if (ws_size >= YP_OFF + 4ull * YP_SLICE) ksplit = 4;
  else if (ws_size >= YP_OFF + 2ull * YP_SLICE) ksplit = 2;
  else if (ws_size >= YP_OFF)                   ksplit = 1;
  else {
    k_out_zero<<<dim3(NNODES * 64 / 256), dim3(256), 0, stream>>>(out);
    return;
  }
  const int tpc = (KT32 + ksplit - 1) / ksplit;

  char* ws = (char*)d_ws;
  bf16*  wctf = (bf16*)(ws + WCT_OFF);
  int*   cnt  = (int*)(ws + CNT_OFF);
  int*   offs = (int*)(ws + OFF_OFF);
  int*   cur  = (int*)(ws + CUR_OFF);
  float* dinv = (float*)(ws + DNV_OFF);
  int*   csr  = (int*)(ws + CSR_OFF);
  bf16*  h1   = (bf16*)(ws + H1_OFF);
  float* hx2  = (float*)(ws + HX2_OFF);
  float* ru   = (float*)(ws + RU_OFF);
  bf16*  h2   = (bf16*)(ws + H2_OFF);
  float* yp   = (float*)(ws + YP_OFF);

  k_zero_i<<<dim3(32), dim3(256), 0, stream>>>(cnt, NNODES);
  k_prep_wctf<<<dim3((KT32 * 12 * 64 + 255) / 256), dim3(256), 0, stream>>>(W1, W2, wctf);
  k_hist<<<dim3((E + 255) / 256), dim3(256), 0, stream>>>(ei, E, cnt);
  k_scan<<<dim3(1), dim3(256), 0, stream>>>(cnt, offs, cur, dinv);
  k_fill<<<dim3((E + 255) / 256), dim3(256), 0, stream>>>(ei, E, cur, csr);
  if (ksplit == 1) {
    k_gemm<<<dim3(NNODES / BMB, 1), dim3(256), 0, stream>>>(x, hid, wctf, nullptr, h1, hx2, tpc);
  } else {
    k_gemm<<<dim3(NNODES / BMB, ksplit), dim3(256), 0, stream>>>(x, hid, wctf, yp, nullptr, nullptr, tpc);
    k_reduce4<<<dim3(NNODES * NCOL / 1024), dim3(256), 0, stream>>>(yp, h1, hx2, ksplit);
  }
  k_scat1<<<dim3(NNODES / 4), dim3(256), 0, stream>>>(h1, offs, csr, dinv, b1, ru);
  k_rh<<<dim3(NNODES / 4), dim3(256), 0, stream>>>(ru, hid, hx2, W2, h2);
  k_scat2<<<dim3(NNODES / 4), dim3(256), 0, stream>>>(h2, offs, csr, dinv, b2, ru, hid, out);
}